// Round 1
// baseline (1059.038 us; speedup 1.0000x reference)
//
#include <hip/hip_runtime.h>

// RNNDecoderP: per-band compaction + (proj affine in dtime) + 2-layer GRU scan + MLP head.
// One wave (64 lanes) per (row, band) sequence; 512 waves total.
// Lane L owns h-element i=L&31; half-waves split each 32-dot (16 MACs each, shfl_xor(32) combine).
// Recurrent weights register-resident; h1/h2 exchanged via 32-float LDS; dtime/y share one 8KB LDS buf.

constexpr int Bn  = 256;
constexpr int Tn  = 2048;
constexpr int Dn  = 64;
constexpr int LBn = 2;
constexpr int DBn = 32;
constexpr int Ln  = 2;
constexpr int Gn  = 96;

#if __has_builtin(__builtin_amdgcn_exp2f)
__device__ __forceinline__ float exp2_fast(float x) { return __builtin_amdgcn_exp2f(x); }
#else
__device__ __forceinline__ float exp2_fast(float x) { return exp2f(x); }
#endif
#if __has_builtin(__builtin_amdgcn_rcpf)
__device__ __forceinline__ float rcp_fast(float x) { return __builtin_amdgcn_rcpf(x); }
#else
__device__ __forceinline__ float rcp_fast(float x) { return 1.0f / x; }
#endif

__device__ __forceinline__ float sigmoid_f(float x) {
  // 1/(1+2^(-x*log2e)); saturates correctly at +/-inf via hw exp2/rcp
  return rcp_fast(1.0f + exp2_fast(-1.4426950408889634f * x));
}
__device__ __forceinline__ float tanh_f(float x) {
  // 1 - 2/(2^(2x*log2e)+1)
  return 1.0f - 2.0f * rcp_fast(1.0f + exp2_fast(2.8853900817779268f * x));
}

__global__ __launch_bounds__(64, 1)
void rnn_decoder(const int* __restrict__ band_ids, const float* __restrict__ dtime,
                 const float* __restrict__ z_last, const float* __restrict__ projW,
                 const float* __restrict__ projB, const float* __restrict__ Wih,
                 const float* __restrict__ Whh, const float* __restrict__ bih,
                 const float* __restrict__ bhh, const float* __restrict__ mW1,
                 const float* __restrict__ mb1, const float* __restrict__ mW2,
                 const float* __restrict__ mb2, float* __restrict__ out) {
  const int b    = blockIdx.x >> 1;
  const int kb   = blockIdx.x & 1;
  const int L    = threadIdx.x;   // 0..63
  const int i    = L & 31;        // owned gate/element index
  const int half = L >> 5;        // which 16-wide half of the dot
  const int koff = half * 16;

  __shared__ float yd[Tn];    // compacted dtime, overwritten in place by y_t
  __shared__ float hsh1[DBn];
  __shared__ float hsh2[DBn];
  __shared__ float xb[DBn];   // projection base (z_last @ projW[:64] + proj_b)
  __shared__ float xs[DBn];   // projection slope (projW[64])

  // ---------------- stable compaction of this band's dtime ----------------
  const int*   brow = band_ids + b * Tn;
  const float* drow = dtime    + b * Tn;
  int cnt = 0;
  int4 bcache[8];
  #pragma unroll
  for (int it = 0; it < 8; ++it) {
    int4 v = ((const int4*)(brow + L * 32))[it];
    bcache[it] = v;
    cnt += (v.x == kb) + (v.y == kb) + (v.z == kb) + (v.w == kb);
  }
  int incl = cnt;
  #pragma unroll
  for (int dlt = 1; dlt < 64; dlt <<= 1) {
    int v = __shfl_up(incl, dlt, 64);
    if (L >= dlt) incl += v;
  }
  int off = incl - cnt;                 // exclusive prefix = stable write offset
  const int n = __shfl(incl, 63, 64);   // total valid steps for this sequence
  #pragma unroll
  for (int it = 0; it < 8; ++it) {
    int4   v  = bcache[it];
    float4 dd = ((const float4*)(drow + L * 32))[it];
    if (v.x == kb) yd[off++] = dd.x;
    if (v.y == kb) yd[off++] = dd.y;
    if (v.z == kb) yd[off++] = dd.z;
    if (v.w == kb) yd[off++] = dd.w;
  }

  // ---------------- projection fold: x_t = xb + d_t * xs ----------------
  {
    const float* pw = projW + (kb * (Dn + 1)) * DBn + i;
    const float* zl = z_last + b * Dn;
    float acc = 0.0f;
    #pragma unroll 8
    for (int k = 0; k < Dn; ++k) acc = fmaf(zl[k], pw[k * DBn], acc);
    xb[i] = acc + projB[kb * DBn + i];   // both halves write identical values
    xs[i] = pw[Dn * DBn];
  }
  __syncthreads();

  // ---------------- register-resident weights (half-rows) ----------------
  float w1r[16], w1z[16], w1n[16];   // Whh layer1, rows i / 32+i / 64+i, cols [koff,koff+16)
  float u2r[16], u2z[16], u2n[16];   // Wih layer2
  float w2r[16], w2z[16], w2n[16];   // Whh layer2
  float m1[16];                      // mW1 half-column i
  {
    const float* whh1 = Whh + ((kb * Ln + 0) * Gn) * DBn;
    const float* wih2 = Wih + ((kb * Ln + 1) * Gn) * DBn;
    const float* whh2 = Whh + ((kb * Ln + 1) * Gn) * DBn;
    #pragma unroll
    for (int q = 0; q < 4; ++q) {
      float4 a;
      a = ((const float4*)(whh1 + (     i) * DBn + koff))[q];
      w1r[4*q+0]=a.x; w1r[4*q+1]=a.y; w1r[4*q+2]=a.z; w1r[4*q+3]=a.w;
      a = ((const float4*)(whh1 + (32 + i) * DBn + koff))[q];
      w1z[4*q+0]=a.x; w1z[4*q+1]=a.y; w1z[4*q+2]=a.z; w1z[4*q+3]=a.w;
      a = ((const float4*)(whh1 + (64 + i) * DBn + koff))[q];
      w1n[4*q+0]=a.x; w1n[4*q+1]=a.y; w1n[4*q+2]=a.z; w1n[4*q+3]=a.w;
      a = ((const float4*)(wih2 + (     i) * DBn + koff))[q];
      u2r[4*q+0]=a.x; u2r[4*q+1]=a.y; u2r[4*q+2]=a.z; u2r[4*q+3]=a.w;
      a = ((const float4*)(wih2 + (32 + i) * DBn + koff))[q];
      u2z[4*q+0]=a.x; u2z[4*q+1]=a.y; u2z[4*q+2]=a.z; u2z[4*q+3]=a.w;
      a = ((const float4*)(wih2 + (64 + i) * DBn + koff))[q];
      u2n[4*q+0]=a.x; u2n[4*q+1]=a.y; u2n[4*q+2]=a.z; u2n[4*q+3]=a.w;
      a = ((const float4*)(whh2 + (     i) * DBn + koff))[q];
      w2r[4*q+0]=a.x; w2r[4*q+1]=a.y; w2r[4*q+2]=a.z; w2r[4*q+3]=a.w;
      a = ((const float4*)(whh2 + (32 + i) * DBn + koff))[q];
      w2z[4*q+0]=a.x; w2z[4*q+1]=a.y; w2z[4*q+2]=a.z; w2z[4*q+3]=a.w;
      a = ((const float4*)(whh2 + (64 + i) * DBn + koff))[q];
      w2n[4*q+0]=a.x; w2n[4*q+1]=a.y; w2n[4*q+2]=a.z; w2n[4*q+3]=a.w;
    }
    #pragma unroll
    for (int q = 0; q < 16; ++q) m1[q] = mW1[(kb * DBn + koff + q) * DBn + i];
  }

  // ---------------- per-gate affine constants for layer-1 input ----------------
  const float* wih1  = Wih + ((kb * Ln + 0) * Gn) * DBn;
  const float* bih1p = bih + (kb * Ln + 0) * Gn;
  const float* bhh1p = bhh + (kb * Ln + 0) * Gn;
  const float* bih2p = bih + (kb * Ln + 1) * Gn;
  const float* bhh2p = bhh + (kb * Ln + 1) * Gn;
  float gb_r = 0, gb_z = 0, gb_n = 0, gs_r = 0, gs_z = 0, gs_n = 0;
  #pragma unroll 4
  for (int j = 0; j < DBn; ++j) {
    float xbv = xb[j], xsv = xs[j];
    float wr = wih1[(     i) * DBn + j];
    float wz = wih1[(32 + i) * DBn + j];
    float wn = wih1[(64 + i) * DBn + j];
    gb_r = fmaf(wr, xbv, gb_r);  gs_r = fmaf(wr, xsv, gs_r);
    gb_z = fmaf(wz, xbv, gb_z);  gs_z = fmaf(wz, xsv, gs_z);
    gb_n = fmaf(wn, xbv, gb_n);  gs_n = fmaf(wn, xsv, gs_n);
  }
  gb_r += bih1p[i]      + bhh1p[i];        // r/z: bih+bhh both additive -> fold
  gb_z += bih1p[32 + i] + bhh1p[32 + i];
  gb_n += bih1p[64 + i];                   // n: bhh sits INSIDE r*(.) -> keep separate
  const float bhh1n = bhh1p[64 + i];
  const float c2r   = bih2p[i]      + bhh2p[i];
  const float c2z   = bih2p[32 + i] + bhh2p[32 + i];
  const float bih2n = bih2p[64 + i];
  const float bhh2n = bhh2p[64 + i];
  const float mb1i  = mb1[kb * DBn + i];
  const float mW2i  = mW2[kb * DBn + i];
  const float mb2v  = mb2[kb];

  // y for h2==0 (covers n==0 and initializes the frozen-tail value)
  float ylast;
  {
    float c = fmaxf(mb1i, 0.0f) * mW2i;
    #pragma unroll
    for (int m = 16; m >= 1; m >>= 1) c += __shfl_xor(c, m, 64);
    ylast = c + mb2v;
  }

  float h1buf[16], h2buf[16];
  #pragma unroll
  for (int q = 0; q < 16; ++q) { h1buf[q] = 0.0f; h2buf[q] = 0.0f; }
  float h1self = 0.0f, h2self = 0.0f;

  // ---------------- sequential scan over valid steps ----------------
  for (int t = 0; t < n; ++t) {
    const float d = yd[t];
    // layer 1 recurrent matvec (half-dot per lane)
    float ar = 0, az = 0, an = 0;
    #pragma unroll
    for (int q = 0; q < 16; ++q) {
      ar = fmaf(w1r[q], h1buf[q], ar);
      az = fmaf(w1z[q], h1buf[q], az);
      an = fmaf(w1n[q], h1buf[q], an);
    }
    ar += __shfl_xor(ar, 32, 64);
    az += __shfl_xor(az, 32, 64);
    an += __shfl_xor(an, 32, 64);
    const float r1  = sigmoid_f(fmaf(d, gs_r, gb_r) + ar);
    const float z1  = sigmoid_f(fmaf(d, gs_z, gb_z) + az);
    const float n1  = tanh_f(fmaf(d, gs_n, gb_n) + r1 * (an + bhh1n));
    const float h1n = fmaf(z1, h1self - n1, n1);   // (1-z)n + z h
    h1self = h1n;
    hsh1[i] = h1n;                                 // lanes i and i+32 write identical value
    __syncthreads();
    #pragma unroll
    for (int q = 0; q < 4; ++q) {
      float4 v = *(const float4*)&hsh1[koff + 4 * q];
      h1buf[4*q+0]=v.x; h1buf[4*q+1]=v.y; h1buf[4*q+2]=v.z; h1buf[4*q+3]=v.w;
    }
    // layer 2: input gates from h1_t, recurrent gates from h2_{t-1}
    float br = 0, bz = 0, bn = 0, cr = 0, cz = 0, cn = 0;
    #pragma unroll
    for (int q = 0; q < 16; ++q) {
      br = fmaf(u2r[q], h1buf[q], br);
      bz = fmaf(u2z[q], h1buf[q], bz);
      bn = fmaf(u2n[q], h1buf[q], bn);
      cr = fmaf(w2r[q], h2buf[q], cr);
      cz = fmaf(w2z[q], h2buf[q], cz);
      cn = fmaf(w2n[q], h2buf[q], cn);
    }
    br += __shfl_xor(br, 32, 64);
    bz += __shfl_xor(bz, 32, 64);
    bn += __shfl_xor(bn, 32, 64);
    cr += __shfl_xor(cr, 32, 64);
    cz += __shfl_xor(cz, 32, 64);
    cn += __shfl_xor(cn, 32, 64);
    const float r2  = sigmoid_f(br + cr + c2r);
    const float z2  = sigmoid_f(bz + cz + c2z);
    const float n2  = tanh_f((bn + bih2n) + r2 * (cn + bhh2n));
    const float h2n = fmaf(z2, h2self - n2, n2);
    h2self = h2n;
    hsh2[i] = h2n;
    __syncthreads();
    #pragma unroll
    for (int q = 0; q < 4; ++q) {
      float4 v = *(const float4*)&hsh2[koff + 4 * q];
      h2buf[4*q+0]=v.x; h2buf[4*q+1]=v.y; h2buf[4*q+2]=v.z; h2buf[4*q+3]=v.w;
    }
    // MLP head: relu(h2 @ mW1 + mb1) @ mW2 + mb2
    float acc = 0.0f;
    #pragma unroll
    for (int q = 0; q < 16; ++q) acc = fmaf(m1[q], h2buf[q], acc);
    acc += __shfl_xor(acc, 32, 64);
    acc += mb1i;
    acc = fmaxf(acc, 0.0f) * mW2i;
    #pragma unroll
    for (int m = 16; m >= 1; m >>= 1) acc += __shfl_xor(acc, m, 64);
    const float y = acc + mb2v;
    ylast = y;
    if (L == 0) yd[t] = y;    // overwrite consumed dtime slot with the output
  }

  // frozen tail + coalesced store
  __syncthreads();
  for (int t = n + L; t < Tn; t += 64) yd[t] = ylast;
  __syncthreads();
  float* orow = out + (kb * Bn + b) * Tn;
  #pragma unroll
  for (int q = 0; q < 8; ++q) {
    const int idx = (q * 64 + L) * 4;
    float4 v = *(const float4*)&yd[idx];
    *(float4*)(orow + idx) = v;
  }
}

extern "C" void kernel_launch(void* const* d_in, const int* in_sizes, int n_in,
                              void* d_out, int out_size, void* d_ws, size_t ws_size,
                              hipStream_t stream) {
  const int*   band_ids = (const int*)  d_in[0];
  const float* dtime    = (const float*)d_in[1];
  const float* z_last   = (const float*)d_in[2];
  const float* projW    = (const float*)d_in[3];
  const float* projB    = (const float*)d_in[4];
  const float* Wih      = (const float*)d_in[5];
  const float* Whh      = (const float*)d_in[6];
  const float* bihp     = (const float*)d_in[7];
  const float* bhhp     = (const float*)d_in[8];
  const float* mW1      = (const float*)d_in[9];
  const float* mb1      = (const float*)d_in[10];
  const float* mW2      = (const float*)d_in[11];
  const float* mb2      = (const float*)d_in[12];
  float* out = (float*)d_out;
  rnn_decoder<<<dim3(Bn * LBn), dim3(64), 0, stream>>>(
      band_ids, dtime, z_last, projW, projB, Wih, Whh, bihp, bhhp,
      mW1, mb1, mW2, mb2, out);
}

// Round 2
// 664.953 us; speedup vs baseline: 1.5927x; 1.5927x over previous
//
#include <hip/hip_runtime.h>

// RNNDecoderP: per-band compaction + (proj affine in dtime) + 2-layer GRU scan + deferred MLP head.
// One wave per (row, band) sequence; 512 waves. Latency-bound -> minimize per-step dep chain:
//  - MLP reduce deferred out of the scan (8 partials/step -> batch reduce after)
//  - L2 recurrent matvec + MLP pipelined to iteration top (depend only on h2_{t-1})
//  - no in-loop barriers (single-wave block, wave-synchronous LDS)
//  - v_pk_fma_f32 matvecs (v2f)

typedef float v2f __attribute__((ext_vector_type(2)));

constexpr int Bn  = 256;
constexpr int Tn  = 2048;
constexpr int Dn  = 64;
constexpr int LBn = 2;
constexpr int DBn = 32;
constexpr int Ln  = 2;
constexpr int Gn  = 96;

#if __has_builtin(__builtin_amdgcn_exp2f)
__device__ __forceinline__ float exp2_fast(float x) { return __builtin_amdgcn_exp2f(x); }
#else
__device__ __forceinline__ float exp2_fast(float x) { return exp2f(x); }
#endif
#if __has_builtin(__builtin_amdgcn_rcpf)
__device__ __forceinline__ float rcp_fast(float x) { return __builtin_amdgcn_rcpf(x); }
#else
__device__ __forceinline__ float rcp_fast(float x) { return 1.0f / x; }
#endif

__device__ __forceinline__ float sigmoid_f(float x) {
  return rcp_fast(1.0f + exp2_fast(-1.4426950408889634f * x));
}
__device__ __forceinline__ float tanh_f(float x) {
  return 1.0f - 2.0f * rcp_fast(1.0f + exp2_fast(2.8853900817779268f * x));
}

__device__ __forceinline__ float dot8(const v2f* __restrict__ w, const v2f* __restrict__ h) {
  v2f a = {0.0f, 0.0f};
  #pragma unroll
  for (int q = 0; q < 8; ++q) a = __builtin_elementwise_fma(w[q], h[q], a);
  return a.x + a.y;
}

__global__ __launch_bounds__(64, 1)
void rnn_decoder(const int* __restrict__ band_ids, const float* __restrict__ dtime,
                 const float* __restrict__ z_last, const float* __restrict__ projW,
                 const float* __restrict__ projB, const float* __restrict__ Wih,
                 const float* __restrict__ Whh, const float* __restrict__ bih,
                 const float* __restrict__ bhh, const float* __restrict__ mW1,
                 const float* __restrict__ mb1, const float* __restrict__ mW2,
                 const float* __restrict__ mb2, float* __restrict__ out) {
  const int b    = blockIdx.x >> 1;
  const int kb   = blockIdx.x & 1;
  const int L    = threadIdx.x;   // 0..63
  const int i    = L & 31;        // owned gate/element index
  const int half = L >> 5;        // which 16-wide half of the dot
  const int koff = half * 16;

  __shared__ float yd[Tn];            // compacted dtime; later overwritten with y
  __shared__ float yc[8 * (Tn + 1)];  // 8 MLP partials per step (slot s = step s-1)
  __shared__ float hsh1[DBn];
  __shared__ float hsh2[DBn];
  __shared__ float xb[DBn];
  __shared__ float xs[DBn];

  // ---------------- stable compaction of this band's dtime ----------------
  const int*   brow = band_ids + b * Tn;
  const float* drow = dtime    + b * Tn;
  int cnt = 0;
  int4 bcache[8];
  #pragma unroll
  for (int it = 0; it < 8; ++it) {
    int4 v = ((const int4*)(brow + L * 32))[it];
    bcache[it] = v;
    cnt += (v.x == kb) + (v.y == kb) + (v.z == kb) + (v.w == kb);
  }
  int incl = cnt;
  #pragma unroll
  for (int dlt = 1; dlt < 64; dlt <<= 1) {
    int v = __shfl_up(incl, dlt, 64);
    if (L >= dlt) incl += v;
  }
  int off = incl - cnt;
  const int n = __shfl(incl, 63, 64);
  #pragma unroll
  for (int it = 0; it < 8; ++it) {
    int4   v  = bcache[it];
    float4 dd = ((const float4*)(drow + L * 32))[it];
    if (v.x == kb) yd[off++] = dd.x;
    if (v.y == kb) yd[off++] = dd.y;
    if (v.z == kb) yd[off++] = dd.z;
    if (v.w == kb) yd[off++] = dd.w;
  }

  // ---------------- projection fold: x_t = xb + d_t * xs ----------------
  {
    const float* pw = projW + (kb * (Dn + 1)) * DBn + i;
    const float* zl = z_last + b * Dn;
    float acc = 0.0f;
    #pragma unroll 8
    for (int k = 0; k < Dn; ++k) acc = fmaf(zl[k], pw[k * DBn], acc);
    xb[i] = acc + projB[kb * DBn + i];
    xs[i] = pw[Dn * DBn];
  }
  __syncthreads();

  // ---------------- register-resident weights (half-rows as v2f) ----------------
  v2f w1r[8], w1z[8], w1n[8];   // Whh layer1
  v2f u2r[8], u2z[8], u2n[8];   // Wih layer2
  v2f w2r[8], w2z[8], w2n[8];   // Whh layer2
  v2f m1p[8];                   // mW1 half-column i
  {
    const float* whh1 = Whh + ((kb * Ln + 0) * Gn) * DBn;
    const float* wih2 = Wih + ((kb * Ln + 1) * Gn) * DBn;
    const float* whh2 = Whh + ((kb * Ln + 1) * Gn) * DBn;
    #pragma unroll
    for (int q = 0; q < 4; ++q) {
      float4 a;
      a = ((const float4*)(whh1 + (     i) * DBn + koff))[q];
      w1r[2*q] = (v2f){a.x, a.y}; w1r[2*q+1] = (v2f){a.z, a.w};
      a = ((const float4*)(whh1 + (32 + i) * DBn + koff))[q];
      w1z[2*q] = (v2f){a.x, a.y}; w1z[2*q+1] = (v2f){a.z, a.w};
      a = ((const float4*)(whh1 + (64 + i) * DBn + koff))[q];
      w1n[2*q] = (v2f){a.x, a.y}; w1n[2*q+1] = (v2f){a.z, a.w};
      a = ((const float4*)(wih2 + (     i) * DBn + koff))[q];
      u2r[2*q] = (v2f){a.x, a.y}; u2r[2*q+1] = (v2f){a.z, a.w};
      a = ((const float4*)(wih2 + (32 + i) * DBn + koff))[q];
      u2z[2*q] = (v2f){a.x, a.y}; u2z[2*q+1] = (v2f){a.z, a.w};
      a = ((const float4*)(wih2 + (64 + i) * DBn + koff))[q];
      u2n[2*q] = (v2f){a.x, a.y}; u2n[2*q+1] = (v2f){a.z, a.w};
      a = ((const float4*)(whh2 + (     i) * DBn + koff))[q];
      w2r[2*q] = (v2f){a.x, a.y}; w2r[2*q+1] = (v2f){a.z, a.w};
      a = ((const float4*)(whh2 + (32 + i) * DBn + koff))[q];
      w2z[2*q] = (v2f){a.x, a.y}; w2z[2*q+1] = (v2f){a.z, a.w};
      a = ((const float4*)(whh2 + (64 + i) * DBn + koff))[q];
      w2n[2*q] = (v2f){a.x, a.y}; w2n[2*q+1] = (v2f){a.z, a.w};
    }
    #pragma unroll
    for (int q = 0; q < 8; ++q)
      m1p[q] = (v2f){ mW1[(kb * DBn + koff + 2*q)     * DBn + i],
                      mW1[(kb * DBn + koff + 2*q + 1) * DBn + i] };
  }

  // ---------------- per-gate affine constants for layer-1 input ----------------
  const float* wih1  = Wih + ((kb * Ln + 0) * Gn) * DBn;
  const float* bih1p = bih + (kb * Ln + 0) * Gn;
  const float* bhh1p = bhh + (kb * Ln + 0) * Gn;
  const float* bih2p = bih + (kb * Ln + 1) * Gn;
  const float* bhh2p = bhh + (kb * Ln + 1) * Gn;
  float gb_r = 0, gb_z = 0, gb_n = 0, gs_r = 0, gs_z = 0, gs_n = 0;
  #pragma unroll 4
  for (int j = 0; j < DBn; ++j) {
    float xbv = xb[j], xsv = xs[j];
    float wr = wih1[(     i) * DBn + j];
    float wz = wih1[(32 + i) * DBn + j];
    float wn = wih1[(64 + i) * DBn + j];
    gb_r = fmaf(wr, xbv, gb_r);  gs_r = fmaf(wr, xsv, gs_r);
    gb_z = fmaf(wz, xbv, gb_z);  gs_z = fmaf(wz, xsv, gs_z);
    gb_n = fmaf(wn, xbv, gb_n);  gs_n = fmaf(wn, xsv, gs_n);
  }
  gb_r += bih1p[i]      + bhh1p[i];
  gb_z += bih1p[32 + i] + bhh1p[32 + i];
  gb_n += bih1p[64 + i];
  const float bhh1n = bhh1p[64 + i];
  const float c2r   = bih2p[i]      + bhh2p[i];
  const float c2z   = bih2p[32 + i] + bhh2p[32 + i];
  const float bih2n = bih2p[64 + i];
  const float bhh2n = bhh2p[64 + i];
  const float mb1i  = mb1[kb * DBn + i];
  const float mW2i  = mW2[kb * DBn + i];
  const float mb2v  = mb2[kb];

  // ---------------- scan state ----------------
  hsh2[i] = 0.0f;                       // h2_{-1} = 0 (read at first iteration top)
  v2f h1buf[8];
  #pragma unroll
  for (int q = 0; q < 8; ++q) h1buf[q] = (v2f){0.0f, 0.0f};
  float h1self = 0.0f, h2self = 0.0f;
  __builtin_amdgcn_wave_barrier();

  // ---------------- sequential scan ----------------
  for (int t = 0; t < n; ++t) {
    // --- top: read h2_{t-1}; deferred MLP for step t-1; L2 recurrent matvec ---
    v2f h2buf[8];
    {
      float4 p0 = *(const float4*)&hsh2[koff];
      float4 p1 = *(const float4*)&hsh2[koff + 4];
      float4 p2 = *(const float4*)&hsh2[koff + 8];
      float4 p3 = *(const float4*)&hsh2[koff + 12];
      h2buf[0] = (v2f){p0.x, p0.y}; h2buf[1] = (v2f){p0.z, p0.w};
      h2buf[2] = (v2f){p1.x, p1.y}; h2buf[3] = (v2f){p1.z, p1.w};
      h2buf[4] = (v2f){p2.x, p2.y}; h2buf[5] = (v2f){p2.z, p2.w};
      h2buf[6] = (v2f){p3.x, p3.y}; h2buf[7] = (v2f){p3.z, p3.w};
    }
    // MLP partials for step t-1 (slot t); slot 0 holds the h2=0 value (unused unless n==0)
    {
      float mh = dot8(m1p, h2buf);
      mh += __shfl_xor(mh, 32, 64);
      float c = fmaxf(mh + mb1i, 0.0f) * mW2i;
      c += __shfl_xor(c, 1, 64);
      c += __shfl_xor(c, 2, 64);
      yc[t * 8 + (i >> 2)] = c;   // 8-way same-address multicast write (identical values)
    }
    // L2 recurrent matvec from h2_{t-1} (off the critical chain; consumed late)
    float cr = dot8(w2r, h2buf); cr += __shfl_xor(cr, 32, 64);
    float cz = dot8(w2z, h2buf); cz += __shfl_xor(cz, 32, 64);
    float cn = dot8(w2n, h2buf); cn += __shfl_xor(cn, 32, 64);

    // --- layer 1 (the critical chain) ---
    const float d = yd[t];
    float ar = dot8(w1r, h1buf); ar += __shfl_xor(ar, 32, 64);
    float az = dot8(w1z, h1buf); az += __shfl_xor(az, 32, 64);
    float an = dot8(w1n, h1buf); an += __shfl_xor(an, 32, 64);
    const float r1  = sigmoid_f(fmaf(d, gs_r, gb_r) + ar);
    const float z1  = sigmoid_f(fmaf(d, gs_z, gb_z) + az);
    const float n1  = tanh_f(fmaf(d, gs_n, gb_n) + r1 * (an + bhh1n));
    h1self = fmaf(z1, h1self - n1, n1);
    hsh1[i] = h1self;
    __builtin_amdgcn_wave_barrier();
    {
      float4 p0 = *(const float4*)&hsh1[koff];
      float4 p1 = *(const float4*)&hsh1[koff + 4];
      float4 p2 = *(const float4*)&hsh1[koff + 8];
      float4 p3 = *(const float4*)&hsh1[koff + 12];
      h1buf[0] = (v2f){p0.x, p0.y}; h1buf[1] = (v2f){p0.z, p0.w};
      h1buf[2] = (v2f){p1.x, p1.y}; h1buf[3] = (v2f){p1.z, p1.w};
      h1buf[4] = (v2f){p2.x, p2.y}; h1buf[5] = (v2f){p2.z, p2.w};
      h1buf[6] = (v2f){p3.x, p3.y}; h1buf[7] = (v2f){p3.z, p3.w};
    }

    // --- layer 2 input gates + update ---
    float br = dot8(u2r, h1buf); br += __shfl_xor(br, 32, 64);
    float bz = dot8(u2z, h1buf); bz += __shfl_xor(bz, 32, 64);
    float bn = dot8(u2n, h1buf); bn += __shfl_xor(bn, 32, 64);
    const float r2 = sigmoid_f(br + cr + c2r);
    const float z2 = sigmoid_f(bz + cz + c2z);
    const float n2 = tanh_f((bn + bih2n) + r2 * (cn + bhh2n));
    h2self = fmaf(z2, h2self - n2, n2);
    hsh2[i] = h2self;
    __builtin_amdgcn_wave_barrier();
  }

  // ---------------- epilogue: last step's MLP (h2_{n-1}; zeros if n==0) ----------------
  {
    v2f h2b[8];
    float4 p0 = *(const float4*)&hsh2[koff];
    float4 p1 = *(const float4*)&hsh2[koff + 4];
    float4 p2 = *(const float4*)&hsh2[koff + 8];
    float4 p3 = *(const float4*)&hsh2[koff + 12];
    h2b[0] = (v2f){p0.x, p0.y}; h2b[1] = (v2f){p0.z, p0.w};
    h2b[2] = (v2f){p1.x, p1.y}; h2b[3] = (v2f){p1.z, p1.w};
    h2b[4] = (v2f){p2.x, p2.y}; h2b[5] = (v2f){p2.z, p2.w};
    h2b[6] = (v2f){p3.x, p3.y}; h2b[7] = (v2f){p3.z, p3.w};
    float mh = dot8(m1p, h2b);
    mh += __shfl_xor(mh, 32, 64);
    float c = fmaxf(mh + mb1i, 0.0f) * mW2i;
    c += __shfl_xor(c, 1, 64);
    c += __shfl_xor(c, 2, 64);
    yc[n * 8 + (i >> 2)] = c;
  }
  __builtin_amdgcn_wave_barrier();

  // ---------------- batch reduce partials -> y, tail fill, store ----------------
  for (int t0 = 0; t0 < n; t0 += 64) {
    const int t = t0 + L;
    if (t < n) {
      float4 A = *(const float4*)&yc[(t + 1) * 8];
      float4 Bv = *(const float4*)&yc[(t + 1) * 8 + 4];
      yd[t] = ((A.x + A.y) + (A.z + A.w)) + ((Bv.x + Bv.y) + (Bv.z + Bv.w)) + mb2v;
    }
  }
  float ylast;
  {
    float4 A = *(const float4*)&yc[n * 8];
    float4 Bv = *(const float4*)&yc[n * 8 + 4];
    ylast = ((A.x + A.y) + (A.z + A.w)) + ((Bv.x + Bv.y) + (Bv.z + Bv.w)) + mb2v;
  }
  for (int t = n + L; t < Tn; t += 64) yd[t] = ylast;
  __builtin_amdgcn_wave_barrier();

  float* orow = out + (kb * Bn + b) * Tn;
  #pragma unroll
  for (int q = 0; q < 8; ++q) {
    const int idx = (q * 64 + L) * 4;
    float4 v = *(const float4*)&yd[idx];
    *(float4*)(orow + idx) = v;
  }
}

extern "C" void kernel_launch(void* const* d_in, const int* in_sizes, int n_in,
                              void* d_out, int out_size, void* d_ws, size_t ws_size,
                              hipStream_t stream) {
  const int*   band_ids = (const int*)  d_in[0];
  const float* dtime    = (const float*)d_in[1];
  const float* z_last   = (const float*)d_in[2];
  const float* projW    = (const float*)d_in[3];
  const float* projB    = (const float*)d_in[4];
  const float* Wih      = (const float*)d_in[5];
  const float* Whh      = (const float*)d_in[6];
  const float* bihp     = (const float*)d_in[7];
  const float* bhhp     = (const float*)d_in[8];
  const float* mW1      = (const float*)d_in[9];
  const float* mb1      = (const float*)d_in[10];
  const float* mW2      = (const float*)d_in[11];
  const float* mb2      = (const float*)d_in[12];
  float* out = (float*)d_out;
  rnn_decoder<<<dim3(Bn * LBn), dim3(64), 0, stream>>>(
      band_ids, dtime, z_last, projW, projB, Wih, Whh, bihp, bhhp,
      mW1, mb1, mW2, mb2, out);
}